// Round 1
// 489.723 us; speedup vs baseline: 1.0029x; 1.0029x over previous
//
#include <hip/hip_runtime.h>

#define N_CLASSES 128

// One 16-lane group per row. Lane j holds float4 j and j+16 of the 128-float
// row (8 elements per lane per array). Single pass:
//   loss = (m + log(sum exp(yh - m))) * sum(y) - sum(y * yh)
// argmax(y): reduce max value jointly with softmax max, then recover the
// first-occurrence index via equality match + min-index reduce.
// Grid = 2048 blocks = exactly 8 blocks/CU -> 32 waves/CU (full occupancy);
// __launch_bounds__(256, 8) caps VGPRs at 64 to guarantee it.
__global__ __launch_bounds__(256, 8) void class_loss_kernel(
    const float* __restrict__ y_hat,
    const float* __restrict__ y,
    float* __restrict__ ws,   // [0..127] class sums, [128..255] class counts
    int B)
{
    __shared__ float s_sum[N_CLASSES];
    __shared__ float s_cnt[N_CLASSES];
    const int tid = threadIdx.x;
    for (int i = tid; i < N_CLASSES; i += blockDim.x) { s_sum[i] = 0.f; s_cnt[i] = 0.f; }
    __syncthreads();

    const int lane    = tid & 15;                                  // lane within 16-lane row-group
    const int group   = (blockIdx.x * blockDim.x + tid) >> 4;      // global row-group id
    const int ngroups = (gridDim.x * blockDim.x) >> 4;

    const float4* __restrict__ ph = (const float4*)y_hat;
    const float4* __restrict__ pt = (const float4*)y;

    for (int row = group; row < B; row += ngroups) {
        const size_t base = (size_t)row * (N_CLASSES / 4);
        const float4 h0 = ph[base + lane];
        const float4 h1 = ph[base + lane + 16];
        const float4 t0 = pt[base + lane];
        const float4 t1 = pt[base + lane + 16];

        // local maxes: m over y_hat (for softmax), bv over y (for argmax)
        float m  = fmaxf(fmaxf(fmaxf(h0.x, h0.y), fmaxf(h0.z, h0.w)),
                         fmaxf(fmaxf(h1.x, h1.y), fmaxf(h1.z, h1.w)));
        float bv = fmaxf(fmaxf(fmaxf(t0.x, t0.y), fmaxf(t0.z, t0.w)),
                         fmaxf(fmaxf(t1.x, t1.y), fmaxf(t1.z, t1.w)));
        #pragma unroll
        for (int o = 8; o >= 1; o >>= 1) {
            m  = fmaxf(m,  __shfl_xor(m,  o));
            bv = fmaxf(bv, __shfl_xor(bv, o));
        }

        // partials: sum exp, dot(y, y_hat), sum y
        float s = __expf(h0.x - m) + __expf(h0.y - m) + __expf(h0.z - m) + __expf(h0.w - m)
                + __expf(h1.x - m) + __expf(h1.y - m) + __expf(h1.z - m) + __expf(h1.w - m);
        float dot = t0.x * h0.x + t0.y * h0.y + t0.z * h0.z + t0.w * h0.w
                  + t1.x * h1.x + t1.y * h1.y + t1.z * h1.z + t1.w * h1.w;
        float sy = (t0.x + t0.y + t0.z + t0.w) + (t1.x + t1.y + t1.z + t1.w);

        // first index where y == bv (descending overwrite -> smallest match)
        const int e0 = lane * 4, e1 = 64 + lane * 4;
        int bi = N_CLASSES;
        bi = (t1.w == bv) ? e1 + 3 : bi;
        bi = (t1.z == bv) ? e1 + 2 : bi;
        bi = (t1.y == bv) ? e1 + 1 : bi;
        bi = (t1.x == bv) ? e1     : bi;
        bi = (t0.w == bv) ? e0 + 3 : bi;
        bi = (t0.z == bv) ? e0 + 2 : bi;
        bi = (t0.y == bv) ? e0 + 1 : bi;
        bi = (t0.x == bv) ? e0     : bi;

        #pragma unroll
        for (int o = 8; o >= 1; o >>= 1) {
            s   += __shfl_xor(s,   o);
            dot += __shfl_xor(dot, o);
            sy  += __shfl_xor(sy,  o);
            bi   = min(bi, __shfl_xor(bi, o));
        }

        if (lane == 0) {
            float loss = (m + __logf(s)) * sy - dot;
            atomicAdd(&s_sum[bi], loss);
            atomicAdd(&s_cnt[bi], 1.0f);
        }
    }

    __syncthreads();
    for (int i = tid; i < N_CLASSES; i += blockDim.x) {
        if (s_cnt[i] > 0.f) {
            atomicAdd(&ws[i], s_sum[i]);
            atomicAdd(&ws[N_CLASSES + i], s_cnt[i]);
        }
    }
}

__global__ void finalize_kernel(const float* __restrict__ ws, float* __restrict__ out) {
    const int c = threadIdx.x;
    if (c < N_CLASSES) {
        float cnt = ws[N_CLASSES + c];
        out[c] = (cnt > 0.f) ? ws[c] / cnt : 0.0f;
    }
}

extern "C" void kernel_launch(void* const* d_in, const int* in_sizes, int n_in,
                              void* d_out, int out_size, void* d_ws, size_t ws_size,
                              hipStream_t stream) {
    const float* y_hat = (const float*)d_in[0];
    const float* y     = (const float*)d_in[1];
    float* ws  = (float*)d_ws;
    float* out = (float*)d_out;
    const int B = in_sizes[0] / N_CLASSES;

    hipMemsetAsync(d_ws, 0, 2 * N_CLASSES * sizeof(float), stream);

    const int blocks = 2048;  // 8 blocks/CU on 256 CUs -> 32 waves/CU
    class_loss_kernel<<<blocks, 256, 0, stream>>>(y_hat, y, ws, B);
    finalize_kernel<<<1, N_CLASSES, 0, stream>>>(ws, out);
}

// Round 2
// 488.772 us; speedup vs baseline: 1.0049x; 1.0019x over previous
//
#include <hip/hip_runtime.h>

#define N_CLASSES 128

// 4 lanes per row. Lane l (l=0..3) holds float4s {l, l+4, ..., l+28} of the
// 32-float4 row: 8 float4 per input array per lane, interleaved so each quad's
// load instruction covers 64B contiguous. All 16 loads issue before any use ->
// 16KB in flight per wave (vs 4KB before). Shuffle reduces are 2 steps (xor 1,2
// within a quad -> DPP, no LDS). Single pass:
//   loss = (m + log(sum exp(yh - m))) * sum(y) - sum(y * yh)
// argmax(y): joint max-value reduce, then first-occurrence index by equality
// match (descending overwrite) + min-index reduce.
__global__ __launch_bounds__(256, 4) void class_loss_kernel(
    const float* __restrict__ y_hat,
    const float* __restrict__ y,
    float* __restrict__ ws,   // [0..127] class sums, [128..255] class counts
    int B)
{
    __shared__ float s_sum[N_CLASSES];
    __shared__ float s_cnt[N_CLASSES];
    const int tid = threadIdx.x;
    for (int i = tid; i < N_CLASSES; i += blockDim.x) { s_sum[i] = 0.f; s_cnt[i] = 0.f; }
    __syncthreads();

    const int lane    = tid & 3;                                   // lane within quad
    const int group   = (blockIdx.x * blockDim.x + tid) >> 2;      // global row id base
    const int ngroups = (gridDim.x * blockDim.x) >> 2;

    const float4* __restrict__ ph = (const float4*)y_hat;
    const float4* __restrict__ pt = (const float4*)y;

    for (int row = group; row < B; row += ngroups) {
        const size_t base = (size_t)row * (N_CLASSES / 4) + lane;

        float4 h[8], t[8];
        #pragma unroll
        for (int k = 0; k < 8; ++k) h[k] = ph[base + 4 * k];
        #pragma unroll
        for (int k = 0; k < 8; ++k) t[k] = pt[base + 4 * k];

        // local maxes: m over y_hat (softmax), bv over y (argmax value)
        float m = -INFINITY, bv = -INFINITY;
        #pragma unroll
        for (int k = 0; k < 8; ++k) {
            m  = fmaxf(m,  fmaxf(fmaxf(h[k].x, h[k].y), fmaxf(h[k].z, h[k].w)));
            bv = fmaxf(bv, fmaxf(fmaxf(t[k].x, t[k].y), fmaxf(t[k].z, t[k].w)));
        }
        m  = fmaxf(m,  __shfl_xor(m,  1));
        m  = fmaxf(m,  __shfl_xor(m,  2));
        bv = fmaxf(bv, __shfl_xor(bv, 1));
        bv = fmaxf(bv, __shfl_xor(bv, 2));

        // partials: sum exp, dot(y, y_hat), sum y
        float s = 0.f, dot = 0.f, sy = 0.f;
        #pragma unroll
        for (int k = 0; k < 8; ++k) {
            s   += __expf(h[k].x - m) + __expf(h[k].y - m)
                 + __expf(h[k].z - m) + __expf(h[k].w - m);
            dot += t[k].x * h[k].x + t[k].y * h[k].y
                 + t[k].z * h[k].z + t[k].w * h[k].w;
            sy  += (t[k].x + t[k].y) + (t[k].z + t[k].w);
        }

        // first index where y == bv: descending overwrite -> smallest match.
        // class index of component c of float4 k in lane l: (l + 4k)*4 + c
        int bi = N_CLASSES;
        #pragma unroll
        for (int k = 7; k >= 0; --k) {
            const int e = (lane + 4 * k) * 4;
            if (t[k].w == bv) bi = e + 3;
            if (t[k].z == bv) bi = e + 2;
            if (t[k].y == bv) bi = e + 1;
            if (t[k].x == bv) bi = e;
        }

        #pragma unroll
        for (int o = 2; o >= 1; o >>= 1) {
            s   += __shfl_xor(s,   o);
            dot += __shfl_xor(dot, o);
            sy  += __shfl_xor(sy,  o);
            bi   = min(bi, __shfl_xor(bi, o));
        }

        if (lane == 0) {
            float loss = (m + __logf(s)) * sy - dot;
            atomicAdd(&s_sum[bi], loss);
            atomicAdd(&s_cnt[bi], 1.0f);
        }
    }

    __syncthreads();
    for (int i = tid; i < N_CLASSES; i += blockDim.x) {
        if (s_cnt[i] > 0.f) {
            atomicAdd(&ws[i], s_sum[i]);
            atomicAdd(&ws[N_CLASSES + i], s_cnt[i]);
        }
    }
}

__global__ void finalize_kernel(const float* __restrict__ ws, float* __restrict__ out) {
    const int c = threadIdx.x;
    if (c < N_CLASSES) {
        float cnt = ws[N_CLASSES + c];
        out[c] = (cnt > 0.f) ? ws[c] / cnt : 0.0f;
    }
}

extern "C" void kernel_launch(void* const* d_in, const int* in_sizes, int n_in,
                              void* d_out, int out_size, void* d_ws, size_t ws_size,
                              hipStream_t stream) {
    const float* y_hat = (const float*)d_in[0];
    const float* y     = (const float*)d_in[1];
    float* ws  = (float*)d_ws;
    float* out = (float*)d_out;
    const int B = in_sizes[0] / N_CLASSES;

    hipMemsetAsync(d_ws, 0, 2 * N_CLASSES * sizeof(float), stream);

    const int blocks = 2048;  // 131072 quads; ~4 rows each at B=500k
    class_loss_kernel<<<blocks, 256, 0, stream>>>(y_hat, y, ws, B);
    finalize_kernel<<<1, N_CLASSES, 0, stream>>>(ws, out);
}